// Round 4
// baseline (96.910 us; speedup 1.0000x reference)
//
#include <hip/hip_runtime.h>
#include <hip/hip_fp16.h>
#include <math.h>

#define BATCH 8
#define NN 512
#define EMBED 128
#define NPOS (BATCH * NN * NN)        // 2,097,152

// u = -x*log2(e); sigmoid(x) = rcp(1 + 2^u); silu(x) = (-ln2*u)*sigmoid.
#define NEG_LOG2E (-1.4426950408889634f)
#define NEG_LN2   (-0.6931471805599453f)
#define PI_F      3.14159265358979323846f

// LUT geometry: F(angle, cost, dur) on [-pi,pi] x [0,1] x [0,1], fp16 values.
#define LA 49                   // 48 angle intervals
#define LC 17                   // 16 cost intervals
#define LD 17                   // 16 dur intervals
#define LUT_N    (LA * LC * LD) // 14161
#define LUT_PAD  14168          // multiple of 8 halves -> 28336 B, uint4-stageable
#define STRIDE_C LA             // 49
#define STRIDE_D (LA * LC)      // 833

// ---------------- Kernel 1: build LUT, one wave per grid point --------------
__global__ __launch_bounds__(256) void build_lut_kernel(
    const float* __restrict__ W1, const float* __restrict__ b1,
    const float* __restrict__ W2, const float* __restrict__ b2,
    __half* __restrict__ lut)
{
    const int wave = threadIdx.x >> 6;
    const int lane = threadIdx.x & 63;
    const int n = blockIdx.x * 4 + wave;
    if (n >= LUT_N) return;

    const int ia  = n % LA;
    const int rem = n / LA;
    const int ic  = rem % LC;
    const int idd = rem / LC;
    const float a = __builtin_fmaf((float)ia, PI_F / 24.0f, -PI_F);
    const float c = (float)ic  * (1.0f / 16.0f);
    const float d = (float)idd * (1.0f / 16.0f);

    float v = 0.0f;
    #pragma unroll
    for (int h = 0; h < 2; h++) {
        const int e = lane + h * 64;
        const float wa = W1[e]           * NEG_LOG2E;
        const float wb = W1[EMBED + e]   * NEG_LOG2E;
        const float wc = W1[2*EMBED + e] * NEG_LOG2E;
        const float bb = b1[e]           * NEG_LOG2E;
        const float w2 = W2[e]           * NEG_LN2;
        float u = __builtin_fmaf(a, wa,
                  __builtin_fmaf(c, wb,
                  __builtin_fmaf(d, wc, bb)));
        float p = __builtin_amdgcn_exp2f(u);
        float r = __builtin_amdgcn_rcpf(1.0f + p);
        v = __builtin_fmaf(u * r, w2, v);
    }
    #pragma unroll
    for (int off = 32; off >= 1; off >>= 1)
        v += __shfl_xor(v, off);
    if (lane == 0) lut[n] = __float2half(v + b2[0]);
}

// ---------------- fast atan2 (err ~1e-4 rad; (0,0) -> 0) --------------------
__device__ __forceinline__ float fast_atan2f(float y, float x) {
    float ax = __builtin_fabsf(x), ay = __builtin_fabsf(y);
    float mx = fmaxf(ax, ay), mn = fminf(ax, ay);
    float t  = (mx > 0.0f) ? mn * __builtin_amdgcn_rcpf(mx) : 0.0f;
    float s  = t * t;
    float r  = __builtin_fmaf(s, __builtin_fmaf(s,
               __builtin_fmaf(s, -0.0851330f, 0.1801410f),
               -0.3302995f), 0.9998660f) * t;
    r = (ay > ax) ? (1.57079632679f - r) : r;
    r = (x < 0.0f) ? (3.14159265359f - r) : r;
    return (y < 0.0f) ? -r : r;
}

// ---------------- Kernel 2: trilinear-interp apply --------------------------
__global__ __launch_bounds__(256) void apply_lut_kernel(
    const float* __restrict__ coords, const float* __restrict__ cost,
    const float* __restrict__ dur, const __half* __restrict__ lutG,
    float* __restrict__ out)
{
    __shared__ __half lutH[LUT_PAD];   // 28,336 B -> 4+ blocks/CU

    // 8 consecutive positions per thread; rows are 512 wide, no row-crossing.
    const int start = blockIdx.x * 2048 + threadIdx.x * 8;
    const int b   = start >> 18;
    const int rem = start & (NN * NN - 1);
    const int i   = rem >> 9;
    const int j0  = rem & (NN - 1);

    const float2* c2 = (const float2*)coords;
    const float2 ci = c2[b * NN + i];
    const float4* cj4 = (const float4*)(c2 + b * NN + j0);
    float4 q0 = cj4[0], q1 = cj4[1], q2 = cj4[2], q3 = cj4[3];
    const float4* cs4 = (const float4*)(cost + start);
    const float4* du4 = (const float4*)(dur + start);
    float4 cA = cs4[0], cB = cs4[1];
    float4 dA = du4[0], dB = du4[1];

    {   // stage LUT (global fp16 -> LDS) as uint4: 1771 vec loads / 256 thr
        const uint4* s4 = (const uint4*)lutG;
        uint4* d4 = (uint4*)lutH;
        #pragma unroll
        for (int it = 0; it < 7; it++) {
            int idx = it * 256 + threadIdx.x;
            if (idx < LUT_PAD / 8) d4[idx] = s4[idx];
        }
    }
    __syncthreads();

    const float cjx[8] = {q0.x, q0.z, q1.x, q1.z, q2.x, q2.z, q3.x, q3.z};
    const float cjy[8] = {q0.y, q0.w, q1.y, q1.w, q2.y, q2.w, q3.y, q3.w};
    const float cs[8] = {cA.x, cA.y, cA.z, cA.w, cB.x, cB.y, cB.z, cB.w};
    const float dd[8] = {dA.x, dA.y, dA.z, dA.w, dB.x, dB.y, dB.z, dB.w};

    float res[8];
    #pragma unroll
    for (int k = 0; k < 8; k++) {
        float ang = fast_atan2f(ci.y - cjy[k], ci.x - cjx[k]);
        float s = __builtin_fmaf(ang, 24.0f / PI_F, 24.0f);   // [0,48]
        int ia = (int)s; ia = ia < 47 ? ia : 47;
        float fa = s - (float)ia;
        float tc = cs[k] * 16.0f;
        int ic = (int)tc; ic = ic < 15 ? ic : 15;
        float fc = tc - (float)ic;
        float td = dd[k] * 16.0f;
        int idd = (int)td; idd = idd < 15 ? idd : 15;
        float fd = td - (float)idd;

        const __half* p = &lutH[idd * STRIDE_D + ic * STRIDE_C + ia];
        float v000 = __half2float(p[0]);
        float v100 = __half2float(p[1]);
        float v010 = __half2float(p[STRIDE_C]);
        float v110 = __half2float(p[STRIDE_C + 1]);
        float v001 = __half2float(p[STRIDE_D]);
        float v101 = __half2float(p[STRIDE_D + 1]);
        float v011 = __half2float(p[STRIDE_D + STRIDE_C]);
        float v111 = __half2float(p[STRIDE_D + STRIDE_C + 1]);

        float x00 = __builtin_fmaf(fa, v100 - v000, v000);
        float x10 = __builtin_fmaf(fa, v110 - v010, v010);
        float x01 = __builtin_fmaf(fa, v101 - v001, v001);
        float x11 = __builtin_fmaf(fa, v111 - v011, v011);
        float y0  = __builtin_fmaf(fc, x10 - x00, x00);
        float y1  = __builtin_fmaf(fc, x11 - x01, x01);
        res[k]    = __builtin_fmaf(fd, y1 - y0, y0);
    }

    float4* o4 = (float4*)(out + start);
    o4[0] = make_float4(res[0], res[1], res[2], res[3]);
    o4[1] = make_float4(res[4], res[5], res[6], res[7]);
}

// ---------------- Fallback: exact kernel, used if ws too small --------------
#define FB_PPT 4
#define FB_POS_PER_BLOCK (FB_PPT * 256)
__global__ __launch_bounds__(256) void exact_kernel(
    const float* __restrict__ coords, const float* __restrict__ cost,
    const float* __restrict__ dur, const float* __restrict__ W1,
    const float* __restrict__ b1, const float* __restrict__ W2,
    const float* __restrict__ b2, float* __restrict__ out)
{
    __shared__ float4 wpk[EMBED];
    __shared__ float  w2s[EMBED];
    const int tid = threadIdx.x;
    if (tid < EMBED) {
        wpk[tid] = make_float4(W1[tid] * NEG_LOG2E, W1[EMBED + tid] * NEG_LOG2E,
                               W1[2*EMBED + tid] * NEG_LOG2E, b1[tid] * NEG_LOG2E);
        w2s[tid] = W2[tid] * NEG_LN2;
    }
    __syncthreads();
    const float bias2 = b2[0];
    const int base = blockIdx.x * FB_POS_PER_BLOCK + tid;
    float ang[FB_PPT], cs[FB_PPT], du[FB_PPT], acc[FB_PPT];
    const float2* c2 = (const float2*)coords;
    #pragma unroll
    for (int k = 0; k < FB_PPT; k++) {
        int pos = base + k * 256;
        int b = pos >> 18, rem = pos & (NN*NN - 1);
        int i = rem >> 9, j = rem & (NN - 1);
        float2 ci = c2[b * NN + i];
        float2 cj = c2[b * NN + j];
        ang[k] = atan2f(ci.y - cj.y, ci.x - cj.x);
        cs[k] = cost[pos]; du[k] = dur[pos]; acc[k] = bias2;
    }
    #pragma unroll 4
    for (int e = 0; e < EMBED; e++) {
        float4 w = wpk[e]; float w2 = w2s[e];
        #pragma unroll
        for (int k = 0; k < FB_PPT; k++) {
            float u = __builtin_fmaf(ang[k], w.x,
                      __builtin_fmaf(cs[k], w.y,
                      __builtin_fmaf(du[k], w.z, w.w)));
            float p = __builtin_amdgcn_exp2f(u);
            float r = __builtin_amdgcn_rcpf(1.0f + p);
            acc[k] = __builtin_fmaf(u * r, w2, acc[k]);
        }
    }
    #pragma unroll
    for (int k = 0; k < FB_PPT; k++) out[base + k * 256] = acc[k];
}

extern "C" void kernel_launch(void* const* d_in, const int* in_sizes, int n_in,
                              void* d_out, int out_size, void* d_ws, size_t ws_size,
                              hipStream_t stream) {
    const float* coords = (const float*)d_in[0];
    const float* cost   = (const float*)d_in[1];
    const float* dur    = (const float*)d_in[2];
    const float* W1     = (const float*)d_in[3];
    const float* b1     = (const float*)d_in[4];
    const float* W2     = (const float*)d_in[5];
    const float* b2     = (const float*)d_in[6];
    float* out = (float*)d_out;

    if (ws_size >= (size_t)LUT_PAD * sizeof(__half)) {
        __half* lut = (__half*)d_ws;
        build_lut_kernel<<<(LUT_N + 3) / 4, 256, 0, stream>>>(W1, b1, W2, b2, lut);
        apply_lut_kernel<<<NPOS / 2048, 256, 0, stream>>>(coords, cost, dur, lut, out);
    } else {
        exact_kernel<<<NPOS / FB_POS_PER_BLOCK, 256, 0, stream>>>(
            coords, cost, dur, W1, b1, W2, b2, out);
    }
}

// Round 5
// 87.679 us; speedup vs baseline: 1.1053x; 1.1053x over previous
//
#include <hip/hip_runtime.h>
#include <math.h>

#define BATCH 8
#define NN 512
#define EMBED 128
#define NPOS (BATCH * NN * NN)        // 2,097,152

// u = -x*log2(e); sigmoid(x) = rcp(1 + 2^u); silu(x) = (-ln2*u)*sigmoid.
#define NEG_LOG2E (-1.4426950408889634f)
#define NEG_LN2   (-0.6931471805599453f)
#define PI_F      3.14159265358979323846f

// LUT geometry: F(angle, cost, dur) on [-pi,pi] x [0,1] x [0,1], fp32 values.
#define LA 49                   // 48 angle intervals
#define LC 17                   // 16 cost intervals
#define LD 17                   // 16 dur intervals
#define LUT_N    (LA * LC * LD) // 14161 floats
#define LUT_PAD  14336          // 56 KB: 3584 float4 = 14 full 256-thread rounds
#define STRIDE_C LA             // 49
#define STRIDE_D (LA * LC)      // 833

// ---------------- Kernel 1: build LUT, one wave per grid point --------------
__global__ __launch_bounds__(256) void build_lut_kernel(
    const float* __restrict__ W1, const float* __restrict__ b1,
    const float* __restrict__ W2, const float* __restrict__ b2,
    float* __restrict__ lut)
{
    const int wave = threadIdx.x >> 6;
    const int lane = threadIdx.x & 63;
    const int n = blockIdx.x * 4 + wave;
    if (n >= LUT_N) return;

    const int ia  = n % LA;
    const int rem = n / LA;
    const int ic  = rem % LC;
    const int idd = rem / LC;
    const float a = __builtin_fmaf((float)ia, PI_F / 24.0f, -PI_F);
    const float c = (float)ic  * (1.0f / 16.0f);
    const float d = (float)idd * (1.0f / 16.0f);

    float v = 0.0f;
    #pragma unroll
    for (int h = 0; h < 2; h++) {
        const int e = lane + h * 64;
        const float wa = W1[e]           * NEG_LOG2E;
        const float wb = W1[EMBED + e]   * NEG_LOG2E;
        const float wc = W1[2*EMBED + e] * NEG_LOG2E;
        const float bb = b1[e]           * NEG_LOG2E;
        const float w2 = W2[e]           * NEG_LN2;
        float u = __builtin_fmaf(a, wa,
                  __builtin_fmaf(c, wb,
                  __builtin_fmaf(d, wc, bb)));
        float p = __builtin_amdgcn_exp2f(u);
        float r = __builtin_amdgcn_rcpf(1.0f + p);
        v = __builtin_fmaf(u * r, w2, v);
    }
    #pragma unroll
    for (int off = 32; off >= 1; off >>= 1)
        v += __shfl_xor(v, off);
    if (lane == 0) lut[n] = v + b2[0];
}

// ---------------- fast atan2 (err ~1e-4 rad; (0,0) -> 0) --------------------
__device__ __forceinline__ float fast_atan2f(float y, float x) {
    float ax = __builtin_fabsf(x), ay = __builtin_fabsf(y);
    float mx = fmaxf(ax, ay), mn = fminf(ax, ay);
    float t  = (mx > 0.0f) ? mn * __builtin_amdgcn_rcpf(mx) : 0.0f;
    float s  = t * t;
    float r  = __builtin_fmaf(s, __builtin_fmaf(s,
               __builtin_fmaf(s, -0.0851330f, 0.1801410f),
               -0.3302995f), 0.9998660f) * t;
    r = (ay > ax) ? (1.57079632679f - r) : r;
    r = (x < 0.0f) ? (3.14159265359f - r) : r;
    return (y < 0.0f) ? -r : r;
}

// ---------------- Kernel 2: trilinear-interp apply --------------------------
// 512 blocks x 256 thr; each thread: 4 unit-stride float4 chunks (16 pos).
__global__ __launch_bounds__(256) void apply_lut_kernel(
    const float* __restrict__ coords, const float* __restrict__ cost,
    const float* __restrict__ dur, const float* __restrict__ lutG,
    float* __restrict__ out)
{
    __shared__ float lutH[LUT_PAD];   // 57,344 B -> 2 blocks/CU

    const int tid = threadIdx.x;
    {   // stage LUT: exactly 14 full float4 rounds, no predication
        const float4* s4 = (const float4*)lutG;
        float4* d4 = (float4*)lutH;
        #pragma unroll
        for (int it = 0; it < 14; it++)
            d4[it * 256 + tid] = s4[it * 256 + tid];
    }
    __syncthreads();

    const int blockStart = blockIdx.x * 4096;      // 4096 divides 512^2
    const int b = blockStart >> 18;
    const float2* cb = (const float2*)coords + b * NN;

    #pragma unroll
    for (int g = 0; g < 4; g++) {
        const int start = blockStart + g * 1024 + tid * 4;  // unit-stride/lane
        const int rem = start & (NN * NN - 1);
        const int i   = rem >> 9;
        const int j   = rem & (NN - 1);                     // multiple of 4

        const float2 ci = cb[i];
        const float4* cj4 = (const float4*)(cb + j);        // 32B-aligned
        float4 cjA = cj4[0], cjB = cj4[1];   // (x0,y0,x1,y1),(x2,y2,x3,y3)
        float4 cA = *(const float4*)(cost + start);
        float4 dA = *(const float4*)(dur + start);

        const float cjx[4] = {cjA.x, cjA.z, cjB.x, cjB.z};
        const float cjy[4] = {cjA.y, cjA.w, cjB.y, cjB.w};
        const float cs[4]  = {cA.x, cA.y, cA.z, cA.w};
        const float dd[4]  = {dA.x, dA.y, dA.z, dA.w};

        float res[4];
        #pragma unroll
        for (int k = 0; k < 4; k++) {
            float ang = fast_atan2f(ci.y - cjy[k], ci.x - cjx[k]);
            float s = __builtin_fmaf(ang, 24.0f / PI_F, 24.0f);   // [0,48]
            int ia = (int)s; ia = ia < 47 ? ia : 47;
            float fa = s - (float)ia;
            float tc = cs[k] * 16.0f;
            int ic = (int)tc; ic = ic < 15 ? ic : 15;
            float fc = tc - (float)ic;
            float td = dd[k] * 16.0f;
            int idd = (int)td; idd = idd < 15 ? idd : 15;
            float fd = td - (float)idd;

            const float* p = &lutH[idd * STRIDE_D + ic * STRIDE_C + ia];
            float v000 = p[0],                   v100 = p[1];
            float v010 = p[STRIDE_C],            v110 = p[STRIDE_C + 1];
            float v001 = p[STRIDE_D],            v101 = p[STRIDE_D + 1];
            float v011 = p[STRIDE_D + STRIDE_C], v111 = p[STRIDE_D + STRIDE_C + 1];

            float x00 = __builtin_fmaf(fa, v100 - v000, v000);
            float x10 = __builtin_fmaf(fa, v110 - v010, v010);
            float x01 = __builtin_fmaf(fa, v101 - v001, v001);
            float x11 = __builtin_fmaf(fa, v111 - v011, v011);
            float y0  = __builtin_fmaf(fc, x10 - x00, x00);
            float y1  = __builtin_fmaf(fc, x11 - x01, x01);
            res[k]    = __builtin_fmaf(fd, y1 - y0, y0);
        }

        *(float4*)(out + start) = make_float4(res[0], res[1], res[2], res[3]);
    }
}

// ---------------- Fallback: exact kernel, used if ws too small --------------
#define FB_PPT 4
#define FB_POS_PER_BLOCK (FB_PPT * 256)
__global__ __launch_bounds__(256) void exact_kernel(
    const float* __restrict__ coords, const float* __restrict__ cost,
    const float* __restrict__ dur, const float* __restrict__ W1,
    const float* __restrict__ b1, const float* __restrict__ W2,
    const float* __restrict__ b2, float* __restrict__ out)
{
    __shared__ float4 wpk[EMBED];
    __shared__ float  w2s[EMBED];
    const int tid = threadIdx.x;
    if (tid < EMBED) {
        wpk[tid] = make_float4(W1[tid] * NEG_LOG2E, W1[EMBED + tid] * NEG_LOG2E,
                               W1[2*EMBED + tid] * NEG_LOG2E, b1[tid] * NEG_LOG2E);
        w2s[tid] = W2[tid] * NEG_LN2;
    }
    __syncthreads();
    const float bias2 = b2[0];
    const int base = blockIdx.x * FB_POS_PER_BLOCK + tid;
    float ang[FB_PPT], cs[FB_PPT], du[FB_PPT], acc[FB_PPT];
    const float2* c2 = (const float2*)coords;
    #pragma unroll
    for (int k = 0; k < FB_PPT; k++) {
        int pos = base + k * 256;
        int b = pos >> 18, rem = pos & (NN*NN - 1);
        int i = rem >> 9, j = rem & (NN - 1);
        float2 ci = c2[b * NN + i];
        float2 cj = c2[b * NN + j];
        ang[k] = atan2f(ci.y - cj.y, ci.x - cj.x);
        cs[k] = cost[pos]; du[k] = dur[pos]; acc[k] = bias2;
    }
    #pragma unroll 4
    for (int e = 0; e < EMBED; e++) {
        float4 w = wpk[e]; float w2 = w2s[e];
        #pragma unroll
        for (int k = 0; k < FB_PPT; k++) {
            float u = __builtin_fmaf(ang[k], w.x,
                      __builtin_fmaf(cs[k], w.y,
                      __builtin_fmaf(du[k], w.z, w.w)));
            float p = __builtin_amdgcn_exp2f(u);
            float r = __builtin_amdgcn_rcpf(1.0f + p);
            acc[k] = __builtin_fmaf(u * r, w2, acc[k]);
        }
    }
    #pragma unroll
    for (int k = 0; k < FB_PPT; k++) out[base + k * 256] = acc[k];
}

extern "C" void kernel_launch(void* const* d_in, const int* in_sizes, int n_in,
                              void* d_out, int out_size, void* d_ws, size_t ws_size,
                              hipStream_t stream) {
    const float* coords = (const float*)d_in[0];
    const float* cost   = (const float*)d_in[1];
    const float* dur    = (const float*)d_in[2];
    const float* W1     = (const float*)d_in[3];
    const float* b1     = (const float*)d_in[4];
    const float* W2     = (const float*)d_in[5];
    const float* b2     = (const float*)d_in[6];
    float* out = (float*)d_out;

    if (ws_size >= (size_t)LUT_PAD * sizeof(float)) {
        float* lut = (float*)d_ws;
        build_lut_kernel<<<(LUT_N + 3) / 4, 256, 0, stream>>>(W1, b1, W2, b2, lut);
        apply_lut_kernel<<<NPOS / 4096, 256, 0, stream>>>(coords, cost, dur, lut, out);
    } else {
        exact_kernel<<<NPOS / FB_POS_PER_BLOCK, 256, 0, stream>>>(
            coords, cost, dur, W1, b1, W2, b2, out);
    }
}

// Round 6
// 85.085 us; speedup vs baseline: 1.1390x; 1.0305x over previous
//
#include <hip/hip_runtime.h>
#include <hip/hip_fp16.h>
#include <math.h>

#define BATCH 8
#define NN 512
#define EMBED 128
#define NPOS (BATCH * NN * NN)        // 2,097,152

#define NEG_LOG2E (-1.4426950408889634f)
#define NEG_LN2   (-0.6931471805599453f)
#define PI_F      3.14159265358979323846f

// LUT: F(angle, cost, dur) on [-pi,pi] x [0,1] x [0,1].
// Element (id,ic,ia) is a half2: (F[ia], F[ia+1]) -> one b32 gather per corner pair.
#define LA 33                   // 32 angle intervals
#define LC 17                   // 16 cost intervals
#define LD 17                   // 16 dur intervals
#define LUT_N    (LA * LC * LD) // 9537 half2 words
#define LUT_PAD  9728           // pad to 2432 uint4 (38,912 B LDS -> 4 blocks/CU)
#define STRIDE_C LA             // 33
#define STRIDE_D (LA * LC)      // 561

// ---------------- Kernel 1: build LUT, one wave per grid point --------------
__global__ __launch_bounds__(256) void build_lut_kernel(
    const float* __restrict__ W1, const float* __restrict__ b1,
    const float* __restrict__ W2, const float* __restrict__ b2,
    __half* __restrict__ lut)    // 2*LUT_N halves
{
    const int wave = threadIdx.x >> 6;
    const int lane = threadIdx.x & 63;
    const int n = blockIdx.x * 4 + wave;
    if (n >= LUT_N) return;

    const int ia  = n % LA;
    const int rem = n / LA;
    const int ic  = rem % LC;
    const int idd = rem / LC;
    const float a = __builtin_fmaf((float)ia, PI_F / 16.0f, -PI_F);
    const float c = (float)ic  * (1.0f / 16.0f);
    const float d = (float)idd * (1.0f / 16.0f);

    float v = 0.0f;
    #pragma unroll
    for (int h = 0; h < 2; h++) {
        const int e = lane + h * 64;
        const float wa = W1[e]           * NEG_LOG2E;
        const float wb = W1[EMBED + e]   * NEG_LOG2E;
        const float wc = W1[2*EMBED + e] * NEG_LOG2E;
        const float bb = b1[e]           * NEG_LOG2E;
        const float w2 = W2[e]           * NEG_LN2;
        float u = __builtin_fmaf(a, wa,
                  __builtin_fmaf(c, wb,
                  __builtin_fmaf(d, wc, bb)));
        float p = __builtin_amdgcn_exp2f(u);
        float r = __builtin_amdgcn_rcpf(1.0f + p);
        v = __builtin_fmaf(u * r, w2, v);
    }
    #pragma unroll
    for (int off = 32; off >= 1; off >>= 1)
        v += __shfl_xor(v, off);

    if (lane == 0) {
        __half hv = __float2half(v + b2[0]);
        lut[2 * n] = hv;                      // entry n .x = F(ia)
        if (ia > 0) lut[2 * n - 1] = hv;      // entry n-1 .y = F((ia-1)+1)
    }
}

// ---------------- fast atan2 (deg-11 minimax, err ~2e-6 rad; (0,0)->0) ------
__device__ __forceinline__ float fast_atan2f(float y, float x) {
    float ax = __builtin_fabsf(x), ay = __builtin_fabsf(y);
    float mx = fmaxf(ax, ay), mn = fminf(ax, ay);
    float t  = (mx > 0.0f) ? mn * __builtin_amdgcn_rcpf(mx) : 0.0f;
    float s  = t * t;
    float r  = __builtin_fmaf(s, __builtin_fmaf(s,
               __builtin_fmaf(s, __builtin_fmaf(s,
               __builtin_fmaf(s, -0.0117212f, 0.05265332f),
               -0.11643287f), 0.19354346f), -0.33262347f), 0.99997726f) * t;
    r = (ay > ax) ? (1.57079632679f - r) : r;
    r = (x < 0.0f) ? (3.14159265359f - r) : r;
    return (y < 0.0f) ? -r : r;
}

// ---------------- Kernel 2: trilinear-interp apply --------------------------
// 1024 blocks x 256 thr; each thread: 2 unit-stride float4 chunks (8 pos).
__global__ __launch_bounds__(256) void apply_lut_kernel(
    const float* __restrict__ coords, const float* __restrict__ cost,
    const float* __restrict__ dur, const __half2* __restrict__ lutG,
    float* __restrict__ out)
{
    __shared__ __half2 lutH[LUT_PAD];   // 38,912 B

    const int tid = threadIdx.x;
    {   // stage LUT: 2432 uint4 (reads a bit past LUT_N into ws, harmless)
        const uint4* s4 = (const uint4*)lutG;
        uint4* d4 = (uint4*)lutH;
        #pragma unroll
        for (int it = 0; it < 10; it++) {
            int idx = it * 256 + tid;
            if (idx < LUT_PAD / 4) d4[idx] = s4[idx];
        }
    }
    __syncthreads();

    const int blockStart = blockIdx.x * 2048;      // divides 512^2
    const int b = blockStart >> 18;
    const float2* cb = (const float2*)coords + b * NN;

    #pragma unroll
    for (int g = 0; g < 2; g++) {
        const int start = blockStart + g * 1024 + tid * 4;  // unit-stride/lane
        const int rem = start & (NN * NN - 1);
        const int i   = rem >> 9;
        const int j   = rem & (NN - 1);                     // multiple of 4

        const float2 ci = cb[i];
        const float4* cj4 = (const float4*)(cb + j);
        float4 cjA = cj4[0], cjB = cj4[1];
        float4 cA = *(const float4*)(cost + start);
        float4 dA = *(const float4*)(dur + start);

        const float cjx[4] = {cjA.x, cjA.z, cjB.x, cjB.z};
        const float cjy[4] = {cjA.y, cjA.w, cjB.y, cjB.w};
        const float cs[4]  = {cA.x, cA.y, cA.z, cA.w};
        const float dd[4]  = {dA.x, dA.y, dA.z, dA.w};

        float res[4];
        #pragma unroll
        for (int k = 0; k < 4; k++) {
            float ang = fast_atan2f(ci.y - cjy[k], ci.x - cjx[k]);
            float s = __builtin_fmaf(ang, 16.0f / PI_F, 16.0f);   // [0,32]
            int ia = (int)s; ia = ia < 31 ? ia : 31;
            float fa = s - (float)ia;
            float tc = cs[k] * 16.0f;
            int ic = (int)tc; ic = ic < 15 ? ic : 15;
            float fc = tc - (float)ic;
            float td = dd[k] * 16.0f;
            int idd = (int)td; idd = idd < 15 ? idd : 15;
            float fd = td - (float)idd;

            const __half2* p = &lutH[idd * STRIDE_D + ic * STRIDE_C + ia];
            float2 w00 = __half22float2(p[0]);                    // (v000,v100)
            float2 w10 = __half22float2(p[STRIDE_C]);             // (v010,v110)
            float2 w01 = __half22float2(p[STRIDE_D]);             // (v001,v101)
            float2 w11 = __half22float2(p[STRIDE_D + STRIDE_C]);  // (v011,v111)

            float x00 = __builtin_fmaf(fa, w00.y - w00.x, w00.x);
            float x10 = __builtin_fmaf(fa, w10.y - w10.x, w10.x);
            float x01 = __builtin_fmaf(fa, w01.y - w01.x, w01.x);
            float x11 = __builtin_fmaf(fa, w11.y - w11.x, w11.x);
            float y0  = __builtin_fmaf(fc, x10 - x00, x00);
            float y1  = __builtin_fmaf(fc, x11 - x01, x01);
            res[k]    = __builtin_fmaf(fd, y1 - y0, y0);
        }

        *(float4*)(out + start) = make_float4(res[0], res[1], res[2], res[3]);
    }
}

// ---------------- Fallback: exact kernel, used if ws too small --------------
#define FB_PPT 4
#define FB_POS_PER_BLOCK (FB_PPT * 256)
__global__ __launch_bounds__(256) void exact_kernel(
    const float* __restrict__ coords, const float* __restrict__ cost,
    const float* __restrict__ dur, const float* __restrict__ W1,
    const float* __restrict__ b1, const float* __restrict__ W2,
    const float* __restrict__ b2, float* __restrict__ out)
{
    __shared__ float4 wpk[EMBED];
    __shared__ float  w2s[EMBED];
    const int tid = threadIdx.x;
    if (tid < EMBED) {
        wpk[tid] = make_float4(W1[tid] * NEG_LOG2E, W1[EMBED + tid] * NEG_LOG2E,
                               W1[2*EMBED + tid] * NEG_LOG2E, b1[tid] * NEG_LOG2E);
        w2s[tid] = W2[tid] * NEG_LN2;
    }
    __syncthreads();
    const float bias2 = b2[0];
    const int base = blockIdx.x * FB_POS_PER_BLOCK + tid;
    float ang[FB_PPT], cs[FB_PPT], du[FB_PPT], acc[FB_PPT];
    const float2* c2 = (const float2*)coords;
    #pragma unroll
    for (int k = 0; k < FB_PPT; k++) {
        int pos = base + k * 256;
        int b = pos >> 18, rem = pos & (NN*NN - 1);
        int i = rem >> 9, j = rem & (NN - 1);
        float2 ci = c2[b * NN + i];
        float2 cj = c2[b * NN + j];
        ang[k] = atan2f(ci.y - cj.y, ci.x - cj.x);
        cs[k] = cost[pos]; du[k] = dur[pos]; acc[k] = bias2;
    }
    #pragma unroll 4
    for (int e = 0; e < EMBED; e++) {
        float4 w = wpk[e]; float w2 = w2s[e];
        #pragma unroll
        for (int k = 0; k < FB_PPT; k++) {
            float u = __builtin_fmaf(ang[k], w.x,
                      __builtin_fmaf(cs[k], w.y,
                      __builtin_fmaf(du[k], w.z, w.w)));
            float p = __builtin_amdgcn_exp2f(u);
            float r = __builtin_amdgcn_rcpf(1.0f + p);
            acc[k] = __builtin_fmaf(u * r, w2, acc[k]);
        }
    }
    #pragma unroll
    for (int k = 0; k < FB_PPT; k++) out[base + k * 256] = acc[k];
}

extern "C" void kernel_launch(void* const* d_in, const int* in_sizes, int n_in,
                              void* d_out, int out_size, void* d_ws, size_t ws_size,
                              hipStream_t stream) {
    const float* coords = (const float*)d_in[0];
    const float* cost   = (const float*)d_in[1];
    const float* dur    = (const float*)d_in[2];
    const float* W1     = (const float*)d_in[3];
    const float* b1     = (const float*)d_in[4];
    const float* W2     = (const float*)d_in[5];
    const float* b2     = (const float*)d_in[6];
    float* out = (float*)d_out;

    if (ws_size >= (size_t)LUT_PAD * sizeof(__half2)) {
        __half* lut = (__half*)d_ws;
        build_lut_kernel<<<(LUT_N + 3) / 4, 256, 0, stream>>>(W1, b1, W2, b2, lut);
        apply_lut_kernel<<<NPOS / 2048, 256, 0, stream>>>(
            coords, cost, dur, (const __half2*)lut, out);
    } else {
        exact_kernel<<<NPOS / FB_POS_PER_BLOCK, 256, 0, stream>>>(
            coords, cost, dur, W1, b1, W2, b2, out);
    }
}

// Round 7
// 82.155 us; speedup vs baseline: 1.1796x; 1.0357x over previous
//
#include <hip/hip_runtime.h>
#include <hip/hip_fp16.h>
#include <math.h>

#define BATCH 8
#define NN 512
#define EMBED 128
#define NPOS (BATCH * NN * NN)        // 2,097,152

#define NEG_LOG2E (-1.4426950408889634f)
#define NEG_LN2   (-0.6931471805599453f)
#define PI_F      3.14159265358979323846f

// LUT: F(angle, cost, dur) on [-pi,pi] x [0,1] x [0,1].
// Element (id,ic,ia) is a half2: (F[ia], F[ia+1]).
// 32 angle intervals, 16 cost intervals, 12 dur intervals.
#define LA 33
#define LC 17
#define LD 13
#define LUT_N    (LA * LC * LD)  // 7293 half2 words
#define LUT_PAD  8192            // 32 KB LDS = 2048 uint4 = 8 full 256-thr rounds
#define STRIDE_C LA              // 33
#define STRIDE_D (LA * LC)       // 561

// ---------------- Kernel 1: build LUT, one wave per grid point --------------
__global__ __launch_bounds__(256) void build_lut_kernel(
    const float* __restrict__ W1, const float* __restrict__ b1,
    const float* __restrict__ W2, const float* __restrict__ b2,
    __half* __restrict__ lut)    // 2*LUT_N halves
{
    const int wave = threadIdx.x >> 6;
    const int lane = threadIdx.x & 63;
    const int n = blockIdx.x * 4 + wave;
    if (n >= LUT_N) return;

    const int ia  = n % LA;
    const int rem = n / LA;
    const int ic  = rem % LC;
    const int idd = rem / LC;
    const float a = __builtin_fmaf((float)ia, PI_F / 16.0f, -PI_F);
    const float c = (float)ic  * (1.0f / 16.0f);
    const float d = (float)idd * (1.0f / 12.0f);

    float v = 0.0f;
    #pragma unroll
    for (int h = 0; h < 2; h++) {
        const int e = lane + h * 64;
        const float wa = W1[e]           * NEG_LOG2E;
        const float wb = W1[EMBED + e]   * NEG_LOG2E;
        const float wc = W1[2*EMBED + e] * NEG_LOG2E;
        const float bb = b1[e]           * NEG_LOG2E;
        const float w2 = W2[e]           * NEG_LN2;
        float u = __builtin_fmaf(a, wa,
                  __builtin_fmaf(c, wb,
                  __builtin_fmaf(d, wc, bb)));
        float p = __builtin_amdgcn_exp2f(u);
        float r = __builtin_amdgcn_rcpf(1.0f + p);
        v = __builtin_fmaf(u * r, w2, v);
    }
    #pragma unroll
    for (int off = 32; off >= 1; off >>= 1)
        v += __shfl_xor(v, off);

    if (lane == 0) {
        __half hv = __float2half(v + b2[0]);
        lut[2 * n] = hv;                      // entry n .x = F(ia)
        if (ia > 0) lut[2 * n - 1] = hv;      // entry n-1 .y = F((ia-1)+1)
    }
}

// ---------------- fast atan2 (deg-11 minimax, err ~2e-6 rad; (0,0)->0) ------
__device__ __forceinline__ float fast_atan2f(float y, float x) {
    float ax = __builtin_fabsf(x), ay = __builtin_fabsf(y);
    float mx = fmaxf(ax, ay), mn = fminf(ax, ay);
    float t  = (mx > 0.0f) ? mn * __builtin_amdgcn_rcpf(mx) : 0.0f;
    float s  = t * t;
    float r  = __builtin_fmaf(s, __builtin_fmaf(s,
               __builtin_fmaf(s, __builtin_fmaf(s,
               __builtin_fmaf(s, -0.0117212f, 0.05265332f),
               -0.11643287f), 0.19354346f), -0.33262347f), 0.99997726f) * t;
    r = (ay > ax) ? (1.57079632679f - r) : r;
    r = (x < 0.0f) ? (3.14159265359f - r) : r;
    return (y < 0.0f) ? -r : r;
}

// ---------------- Kernel 2: trilinear-interp apply --------------------------
// 1024 blocks x 256 thr; each thread: 2 unit-stride float4 chunks (8 pos).
// Global loads for chunk g are issued BEFORE they're needed (prefetch ahead
// of the staging barrier / previous chunk's compute) to hide HBM latency.

struct Chunk {
    float4 cjA, cjB;   // coords of 4 consecutive j
    float4 cA, dA;     // cost, dur
    float2 ci;
    int start;
};

__device__ __forceinline__ Chunk load_chunk(const float2* __restrict__ cb,
                                            const float* __restrict__ cost,
                                            const float* __restrict__ dur,
                                            int start) {
    Chunk ch;
    ch.start = start;
    const int rem = start & (NN * NN - 1);
    const int i   = rem >> 9;
    const int j   = rem & (NN - 1);
    ch.ci  = cb[i];
    const float4* cj4 = (const float4*)(cb + j);
    ch.cjA = cj4[0];
    ch.cjB = cj4[1];
    ch.cA  = *(const float4*)(cost + start);
    ch.dA  = *(const float4*)(dur + start);
    return ch;
}

__device__ __forceinline__ void compute_chunk(const Chunk& ch,
                                              const __half2* __restrict__ lutH,
                                              float* __restrict__ out) {
    const float cjx[4] = {ch.cjA.x, ch.cjA.z, ch.cjB.x, ch.cjB.z};
    const float cjy[4] = {ch.cjA.y, ch.cjA.w, ch.cjB.y, ch.cjB.w};
    const float cs[4]  = {ch.cA.x, ch.cA.y, ch.cA.z, ch.cA.w};
    const float dd[4]  = {ch.dA.x, ch.dA.y, ch.dA.z, ch.dA.w};

    float res[4];
    #pragma unroll
    for (int k = 0; k < 4; k++) {
        float ang = fast_atan2f(ch.ci.y - cjy[k], ch.ci.x - cjx[k]);
        float s = __builtin_fmaf(ang, 16.0f / PI_F, 16.0f);   // [0,32]
        int ia = (int)s; ia = ia < 31 ? ia : 31;
        float fa = s - (float)ia;
        float tc = cs[k] * 16.0f;
        int ic = (int)tc; ic = ic < 15 ? ic : 15;
        float fc = tc - (float)ic;
        float td = dd[k] * 12.0f;
        int idd = (int)td; idd = idd < 11 ? idd : 11;
        float fd = td - (float)idd;

        const __half2* p = &lutH[idd * STRIDE_D + ic * STRIDE_C + ia];
        float2 w00 = __half22float2(p[0]);                    // (v000,v100)
        float2 w10 = __half22float2(p[STRIDE_C]);             // (v010,v110)
        float2 w01 = __half22float2(p[STRIDE_D]);             // (v001,v101)
        float2 w11 = __half22float2(p[STRIDE_D + STRIDE_C]);  // (v011,v111)

        float x00 = __builtin_fmaf(fa, w00.y - w00.x, w00.x);
        float x10 = __builtin_fmaf(fa, w10.y - w10.x, w10.x);
        float x01 = __builtin_fmaf(fa, w01.y - w01.x, w01.x);
        float x11 = __builtin_fmaf(fa, w11.y - w11.x, w11.x);
        float y0  = __builtin_fmaf(fc, x10 - x00, x00);
        float y1  = __builtin_fmaf(fc, x11 - x01, x01);
        res[k]    = __builtin_fmaf(fd, y1 - y0, y0);
    }

    *(float4*)(out + ch.start) = make_float4(res[0], res[1], res[2], res[3]);
}

__global__ __launch_bounds__(256) void apply_lut_kernel(
    const float* __restrict__ coords, const float* __restrict__ cost,
    const float* __restrict__ dur, const __half2* __restrict__ lutG,
    float* __restrict__ out)
{
    __shared__ __half2 lutH[LUT_PAD];   // 32,768 B

    const int tid = threadIdx.x;
    const int blockStart = blockIdx.x * 2048;      // divides 512^2
    const int b = blockStart >> 18;
    const float2* cb = (const float2*)coords + b * NN;

    // Prefetch chunk 0's global data before staging (hides HBM latency).
    Chunk c0 = load_chunk(cb, cost, dur, blockStart + tid * 4);

    {   // stage LUT: exactly 8 full uint4 rounds, no predication
        const uint4* s4 = (const uint4*)lutG;
        uint4* d4 = (uint4*)lutH;
        #pragma unroll
        for (int it = 0; it < 8; it++)
            d4[it * 256 + tid] = s4[it * 256 + tid];
    }
    __syncthreads();

    // Prefetch chunk 1 while chunk 0 computes.
    Chunk c1 = load_chunk(cb, cost, dur, blockStart + 1024 + tid * 4);

    compute_chunk(c0, lutH, out);
    compute_chunk(c1, lutH, out);
}

// ---------------- Fallback: exact kernel, used if ws too small --------------
#define FB_PPT 4
#define FB_POS_PER_BLOCK (FB_PPT * 256)
__global__ __launch_bounds__(256) void exact_kernel(
    const float* __restrict__ coords, const float* __restrict__ cost,
    const float* __restrict__ dur, const float* __restrict__ W1,
    const float* __restrict__ b1, const float* __restrict__ W2,
    const float* __restrict__ b2, float* __restrict__ out)
{
    __shared__ float4 wpk[EMBED];
    __shared__ float  w2s[EMBED];
    const int tid = threadIdx.x;
    if (tid < EMBED) {
        wpk[tid] = make_float4(W1[tid] * NEG_LOG2E, W1[EMBED + tid] * NEG_LOG2E,
                               W1[2*EMBED + tid] * NEG_LOG2E, b1[tid] * NEG_LOG2E);
        w2s[tid] = W2[tid] * NEG_LN2;
    }
    __syncthreads();
    const float bias2 = b2[0];
    const int base = blockIdx.x * FB_POS_PER_BLOCK + tid;
    float ang[FB_PPT], cs[FB_PPT], du[FB_PPT], acc[FB_PPT];
    const float2* c2 = (const float2*)coords;
    #pragma unroll
    for (int k = 0; k < FB_PPT; k++) {
        int pos = base + k * 256;
        int b = pos >> 18, rem = pos & (NN*NN - 1);
        int i = rem >> 9, j = rem & (NN - 1);
        float2 ci = c2[b * NN + i];
        float2 cj = c2[b * NN + j];
        ang[k] = atan2f(ci.y - cj.y, ci.x - cj.x);
        cs[k] = cost[pos]; du[k] = dur[pos]; acc[k] = bias2;
    }
    #pragma unroll 4
    for (int e = 0; e < EMBED; e++) {
        float4 w = wpk[e]; float w2 = w2s[e];
        #pragma unroll
        for (int k = 0; k < FB_PPT; k++) {
            float u = __builtin_fmaf(ang[k], w.x,
                      __builtin_fmaf(cs[k], w.y,
                      __builtin_fmaf(du[k], w.z, w.w)));
            float p = __builtin_amdgcn_exp2f(u);
            float r = __builtin_amdgcn_rcpf(1.0f + p);
            acc[k] = __builtin_fmaf(u * r, w2, acc[k]);
        }
    }
    #pragma unroll
    for (int k = 0; k < FB_PPT; k++) out[base + k * 256] = acc[k];
}

extern "C" void kernel_launch(void* const* d_in, const int* in_sizes, int n_in,
                              void* d_out, int out_size, void* d_ws, size_t ws_size,
                              hipStream_t stream) {
    const float* coords = (const float*)d_in[0];
    const float* cost   = (const float*)d_in[1];
    const float* dur    = (const float*)d_in[2];
    const float* W1     = (const float*)d_in[3];
    const float* b1     = (const float*)d_in[4];
    const float* W2     = (const float*)d_in[5];
    const float* b2     = (const float*)d_in[6];
    float* out = (float*)d_out;

    if (ws_size >= (size_t)LUT_PAD * sizeof(__half2)) {
        __half* lut = (__half*)d_ws;
        build_lut_kernel<<<(LUT_N + 3) / 4, 256, 0, stream>>>(W1, b1, W2, b2, lut);
        apply_lut_kernel<<<NPOS / 2048, 256, 0, stream>>>(
            coords, cost, dur, (const __half2*)lut, out);
    } else {
        exact_kernel<<<NPOS / FB_POS_PER_BLOCK, 256, 0, stream>>>(
            coords, cost, dur, W1, b1, W2, b2, out);
    }
}

// Round 8
// 81.604 us; speedup vs baseline: 1.1876x; 1.0067x over previous
//
#include <hip/hip_runtime.h>
#include <hip/hip_fp16.h>
#include <math.h>

#define BATCH 8
#define NN 512
#define EMBED 128
#define NPOS (BATCH * NN * NN)        // 2,097,152

#define NEG_LOG2E (-1.4426950408889634f)
#define NEG_LN2   (-0.6931471805599453f)
#define PI_F      3.14159265358979323846f

// LUT: F(angle, cost, dur) on [-pi,pi] x [0,1] x [0,1].
// Element (id,ic,ia) is a half2: (F[ia], F[ia+1]).
// 32 angle intervals, 12 cost intervals, 12 dur intervals.
#define LA 33
#define LC 13
#define LD 13
#define LUT_N    (LA * LC * LD)  // 5577 half2 words
#define LUT_PAD  6144            // 24 KB LDS = 1536 uint4 = 6 full 256-thr rounds
#define STRIDE_C LA              // 33
#define STRIDE_D (LA * LC)       // 429

// ---------------- Kernel 1: build LUT, one wave per grid point --------------
__global__ __launch_bounds__(256) void build_lut_kernel(
    const float* __restrict__ W1, const float* __restrict__ b1,
    const float* __restrict__ W2, const float* __restrict__ b2,
    __half* __restrict__ lut)    // 2*LUT_N halves
{
    const int wave = threadIdx.x >> 6;
    const int lane = threadIdx.x & 63;
    const int n = blockIdx.x * 4 + wave;
    if (n >= LUT_N) return;

    const int ia  = n % LA;
    const int rem = n / LA;
    const int ic  = rem % LC;
    const int idd = rem / LC;
    const float a = __builtin_fmaf((float)ia, PI_F / 16.0f, -PI_F);
    const float c = (float)ic  * (1.0f / 12.0f);
    const float d = (float)idd * (1.0f / 12.0f);

    float v = 0.0f;
    #pragma unroll
    for (int h = 0; h < 2; h++) {
        const int e = lane + h * 64;
        const float wa = W1[e]           * NEG_LOG2E;
        const float wb = W1[EMBED + e]   * NEG_LOG2E;
        const float wc = W1[2*EMBED + e] * NEG_LOG2E;
        const float bb = b1[e]           * NEG_LOG2E;
        const float w2 = W2[e]           * NEG_LN2;
        float u = __builtin_fmaf(a, wa,
                  __builtin_fmaf(c, wb,
                  __builtin_fmaf(d, wc, bb)));
        float p = __builtin_amdgcn_exp2f(u);
        float r = __builtin_amdgcn_rcpf(1.0f + p);
        v = __builtin_fmaf(u * r, w2, v);
    }
    #pragma unroll
    for (int off = 32; off >= 1; off >>= 1)
        v += __shfl_xor(v, off);

    if (lane == 0) {
        __half hv = __float2half(v + b2[0]);
        lut[2 * n] = hv;                      // entry n .x = F(ia)
        if (ia > 0) lut[2 * n - 1] = hv;      // entry n-1 .y = F((ia-1)+1)
    }
}

// ---------------- fast atan2 (deg-11 minimax, err ~2e-6 rad; (0,0)->0) ------
__device__ __forceinline__ float fast_atan2f(float y, float x) {
    float ax = __builtin_fabsf(x), ay = __builtin_fabsf(y);
    float mx = fmaxf(ax, ay), mn = fminf(ax, ay);
    float t  = (mx > 0.0f) ? mn * __builtin_amdgcn_rcpf(mx) : 0.0f;
    float s  = t * t;
    float r  = __builtin_fmaf(s, __builtin_fmaf(s,
               __builtin_fmaf(s, __builtin_fmaf(s,
               __builtin_fmaf(s, -0.0117212f, 0.05265332f),
               -0.11643287f), 0.19354346f), -0.33262347f), 0.99997726f) * t;
    r = (ay > ax) ? (1.57079632679f - r) : r;
    r = (x < 0.0f) ? (3.14159265359f - r) : r;
    return (y < 0.0f) ? -r : r;
}

// ---------------- Kernel 2: trilinear-interp apply --------------------------
// 1024 blocks x 256 thr; each thread: 2 unit-stride float4 chunks (8 pos).
// ALL global loads for both chunks are issued before the LDS staging loop so
// cold-HBM latency overlaps staging + barrier.

struct Chunk {
    float4 cjA, cjB;   // coords of 4 consecutive j
    float4 cA, dA;     // cost, dur
    float2 ci;
    int start;
};

__device__ __forceinline__ Chunk load_chunk(const float2* __restrict__ cb,
                                            const float* __restrict__ cost,
                                            const float* __restrict__ dur,
                                            int start) {
    Chunk ch;
    ch.start = start;
    const int rem = start & (NN * NN - 1);
    const int i   = rem >> 9;
    const int j   = rem & (NN - 1);
    ch.ci  = cb[i];
    const float4* cj4 = (const float4*)(cb + j);
    ch.cjA = cj4[0];
    ch.cjB = cj4[1];
    ch.cA  = *(const float4*)(cost + start);
    ch.dA  = *(const float4*)(dur + start);
    return ch;
}

__device__ __forceinline__ void compute_chunk(const Chunk& ch,
                                              const __half2* __restrict__ lutH,
                                              float* __restrict__ out) {
    const float cjx[4] = {ch.cjA.x, ch.cjA.z, ch.cjB.x, ch.cjB.z};
    const float cjy[4] = {ch.cjA.y, ch.cjA.w, ch.cjB.y, ch.cjB.w};
    const float cs[4]  = {ch.cA.x, ch.cA.y, ch.cA.z, ch.cA.w};
    const float dd[4]  = {ch.dA.x, ch.dA.y, ch.dA.z, ch.dA.w};

    float res[4];
    #pragma unroll
    for (int k = 0; k < 4; k++) {
        float ang = fast_atan2f(ch.ci.y - cjy[k], ch.ci.x - cjx[k]);
        float s = __builtin_fmaf(ang, 16.0f / PI_F, 16.0f);   // [0,32]
        int ia = (int)s; ia = ia < 31 ? ia : 31;
        float fa = s - (float)ia;
        float tc = cs[k] * 12.0f;
        int ic = (int)tc; ic = ic < 11 ? ic : 11;
        float fc = tc - (float)ic;
        float td = dd[k] * 12.0f;
        int idd = (int)td; idd = idd < 11 ? idd : 11;
        float fd = td - (float)idd;

        const __half2* p = &lutH[idd * STRIDE_D + ic * STRIDE_C + ia];
        float2 w00 = __half22float2(p[0]);                    // (v000,v100)
        float2 w10 = __half22float2(p[STRIDE_C]);             // (v010,v110)
        float2 w01 = __half22float2(p[STRIDE_D]);             // (v001,v101)
        float2 w11 = __half22float2(p[STRIDE_D + STRIDE_C]);  // (v011,v111)

        float x00 = __builtin_fmaf(fa, w00.y - w00.x, w00.x);
        float x10 = __builtin_fmaf(fa, w10.y - w10.x, w10.x);
        float x01 = __builtin_fmaf(fa, w01.y - w01.x, w01.x);
        float x11 = __builtin_fmaf(fa, w11.y - w11.x, w11.x);
        float y0  = __builtin_fmaf(fc, x10 - x00, x00);
        float y1  = __builtin_fmaf(fc, x11 - x01, x01);
        res[k]    = __builtin_fmaf(fd, y1 - y0, y0);
    }

    *(float4*)(out + ch.start) = make_float4(res[0], res[1], res[2], res[3]);
}

__global__ __launch_bounds__(256) void apply_lut_kernel(
    const float* __restrict__ coords, const float* __restrict__ cost,
    const float* __restrict__ dur, const __half2* __restrict__ lutG,
    float* __restrict__ out)
{
    __shared__ __half2 lutH[LUT_PAD];   // 24,576 B

    const int tid = threadIdx.x;
    const int blockStart = blockIdx.x * 2048;      // divides 512^2
    const int b = blockStart >> 18;
    const float2* cb = (const float2*)coords + b * NN;

    // Prefetch BOTH chunks' global data before staging (hides HBM latency).
    Chunk c0 = load_chunk(cb, cost, dur, blockStart + tid * 4);
    Chunk c1 = load_chunk(cb, cost, dur, blockStart + 1024 + tid * 4);

    {   // stage LUT: exactly 6 full uint4 rounds, no predication
        const uint4* s4 = (const uint4*)lutG;
        uint4* d4 = (uint4*)lutH;
        #pragma unroll
        for (int it = 0; it < 6; it++)
            d4[it * 256 + tid] = s4[it * 256 + tid];
    }
    __syncthreads();

    compute_chunk(c0, lutH, out);
    compute_chunk(c1, lutH, out);
}

// ---------------- Fallback: exact kernel, used if ws too small --------------
#define FB_PPT 4
#define FB_POS_PER_BLOCK (FB_PPT * 256)
__global__ __launch_bounds__(256) void exact_kernel(
    const float* __restrict__ coords, const float* __restrict__ cost,
    const float* __restrict__ dur, const float* __restrict__ W1,
    const float* __restrict__ b1, const float* __restrict__ W2,
    const float* __restrict__ b2, float* __restrict__ out)
{
    __shared__ float4 wpk[EMBED];
    __shared__ float  w2s[EMBED];
    const int tid = threadIdx.x;
    if (tid < EMBED) {
        wpk[tid] = make_float4(W1[tid] * NEG_LOG2E, W1[EMBED + tid] * NEG_LOG2E,
                               W1[2*EMBED + tid] * NEG_LOG2E, b1[tid] * NEG_LOG2E);
        w2s[tid] = W2[tid] * NEG_LN2;
    }
    __syncthreads();
    const float bias2 = b2[0];
    const int base = blockIdx.x * FB_POS_PER_BLOCK + tid;
    float ang[FB_PPT], cs[FB_PPT], du[FB_PPT], acc[FB_PPT];
    const float2* c2 = (const float2*)coords;
    #pragma unroll
    for (int k = 0; k < FB_PPT; k++) {
        int pos = base + k * 256;
        int b = pos >> 18, rem = pos & (NN*NN - 1);
        int i = rem >> 9, j = rem & (NN - 1);
        float2 ci = c2[b * NN + i];
        float2 cj = c2[b * NN + j];
        ang[k] = atan2f(ci.y - cj.y, ci.x - cj.x);
        cs[k] = cost[pos]; du[k] = dur[pos]; acc[k] = bias2;
    }
    #pragma unroll 4
    for (int e = 0; e < EMBED; e++) {
        float4 w = wpk[e]; float w2 = w2s[e];
        #pragma unroll
        for (int k = 0; k < FB_PPT; k++) {
            float u = __builtin_fmaf(ang[k], w.x,
                      __builtin_fmaf(cs[k], w.y,
                      __builtin_fmaf(du[k], w.z, w.w)));
            float p = __builtin_amdgcn_exp2f(u);
            float r = __builtin_amdgcn_rcpf(1.0f + p);
            acc[k] = __builtin_fmaf(u * r, w2, acc[k]);
        }
    }
    #pragma unroll
    for (int k = 0; k < FB_PPT; k++) out[base + k * 256] = acc[k];
}

extern "C" void kernel_launch(void* const* d_in, const int* in_sizes, int n_in,
                              void* d_out, int out_size, void* d_ws, size_t ws_size,
                              hipStream_t stream) {
    const float* coords = (const float*)d_in[0];
    const float* cost   = (const float*)d_in[1];
    const float* dur    = (const float*)d_in[2];
    const float* W1     = (const float*)d_in[3];
    const float* b1     = (const float*)d_in[4];
    const float* W2     = (const float*)d_in[5];
    const float* b2     = (const float*)d_in[6];
    float* out = (float*)d_out;

    if (ws_size >= (size_t)LUT_PAD * sizeof(__half2)) {
        __half* lut = (__half*)d_ws;
        build_lut_kernel<<<(LUT_N + 3) / 4, 256, 0, stream>>>(W1, b1, W2, b2, lut);
        apply_lut_kernel<<<NPOS / 2048, 256, 0, stream>>>(
            coords, cost, dur, (const __half2*)lut, out);
    } else {
        exact_kernel<<<NPOS / FB_POS_PER_BLOCK, 256, 0, stream>>>(
            coords, cost, dur, W1, b1, W2, b2, out);
    }
}